// Round 1
// baseline (575.008 us; speedup 1.0000x reference)
//
#include <hip/hip_runtime.h>
#include <hip/hip_bf16.h>
#include <stdint.h>

#define B_ 8
#define T_ 2048
#define C_ 1024
#define H_ 128
#define BT (B_*T_)
#define SCALE 0.08838834764831845f

typedef __attribute__((ext_vector_type(8))) short bf16x8;
typedef __attribute__((ext_vector_type(4))) float f32x4;

__device__ __forceinline__ ushort f2bf(float f) {
  union { float f; uint32_t u; } un; un.f = f;
  return (ushort)((un.u + 0x7fffu + ((un.u >> 16) & 1u)) >> 16);
}

// ---------------- fused QKV projection ----------------
// Computes q = x@Wq, k = x@Wk, v = x@Wv in bf16-MFMA with fp32 accumulate.
// Outputs bf16: qh [BT][128], kh [BT][128], vt [B][128][T] (V transposed).
__global__ __launch_bounds__(256) void proj_kernel(
    const float* __restrict__ x, const float* __restrict__ Wq,
    const float* __restrict__ Wk, const float* __restrict__ Wv,
    ushort* __restrict__ qh, ushort* __restrict__ kh, ushort* __restrict__ vt)
{
  __shared__ __align__(16) ushort xs[64][64];    // [row][k] bf16
  __shared__ __align__(16) ushort wt[384][64];   // [col][k] bf16 (W transposed)
  const int tid  = threadIdx.x;
  const int lane = tid & 63, wave = tid >> 6;
  const int l15  = lane & 15, l4 = lane >> 4;
  const int m0   = blockIdx.x * 64;

  f32x4 acc[24];
  #pragma unroll
  for (int i = 0; i < 24; ++i) acc[i] = f32x4{0.f, 0.f, 0.f, 0.f};

  const float* Ws[3] = {Wq, Wk, Wv};

  for (int k0 = 0; k0 < C_; k0 += 64) {
    __syncthreads();
    // stage x tile [64][64] fp32 -> bf16, float4 loads (coalesced)
    {
      const int c4 = tid & 15, r0 = tid >> 4;
      #pragma unroll
      for (int rr = 0; rr < 4; ++rr) {
        const int r = r0 + 16 * rr;
        float4 v = *reinterpret_cast<const float4*>(
            &x[(size_t)(m0 + r) * C_ + k0 + 4 * c4]);
        ushort4 pk;
        pk.x = f2bf(v.x); pk.y = f2bf(v.y); pk.z = f2bf(v.z); pk.w = f2bf(v.w);
        *reinterpret_cast<ushort4*>(&xs[r][4 * c4]) = pk;
      }
    }
    // stage W^T [384][64] fp32 -> bf16 (coalesced over cols)
    for (int w = 0; w < 3; ++w) {
      const float* W = Ws[w];
      #pragma unroll
      for (int i = 0; i < 32; ++i) {
        const int flat = tid + 256 * i;       // 0..8191
        const int kk = flat >> 7, col = flat & 127;
        wt[w * 128 + col][kk] = f2bf(W[(size_t)(k0 + kk) * H_ + col]);
      }
    }
    __syncthreads();
    const int row = wave * 16 + l15;
    const int kin = l4 * 8;
    bf16x8 a0 = *reinterpret_cast<const bf16x8*>(&xs[row][kin]);
    bf16x8 a1 = *reinterpret_cast<const bf16x8*>(&xs[row][32 + kin]);
    #pragma unroll
    for (int ct = 0; ct < 24; ++ct) {
      bf16x8 b0 = *reinterpret_cast<const bf16x8*>(&wt[ct * 16 + l15][kin]);
      bf16x8 b1 = *reinterpret_cast<const bf16x8*>(&wt[ct * 16 + l15][32 + kin]);
      acc[ct] = __builtin_amdgcn_mfma_f32_16x16x32_bf16(a0, b0, acc[ct], 0, 0, 0);
      acc[ct] = __builtin_amdgcn_mfma_f32_16x16x32_bf16(a1, b1, acc[ct], 0, 0, 0);
    }
  }
  // epilogue: C/D layout col=lane&15, row=(lane>>4)*4+reg  [m89-verified]
  #pragma unroll
  for (int ct = 0; ct < 24; ++ct) {
    const int colg = ct * 16 + l15;
    #pragma unroll
    for (int reg = 0; reg < 4; ++reg) {
      const int row = m0 + wave * 16 + l4 * 4 + reg;
      const ushort hv = f2bf(acc[ct][reg]);
      if (colg < 128)      qh[(size_t)row * H_ + colg] = hv;
      else if (colg < 256) kh[(size_t)row * H_ + (colg - 128)] = hv;
      else {
        const int h = colg - 256, bb = row >> 11, t = row & 2047;
        vt[((size_t)bb * H_ + h) * T_ + t] = hv;
      }
    }
  }
}

// ---------------- flash attention (causal) ----------------
// 1 block = 64 query rows of one batch; 4 waves x 16 rows each.
__global__ __launch_bounds__(256) void attn_kernel(
    const ushort* __restrict__ qh, const ushort* __restrict__ kh,
    const ushort* __restrict__ vt, float* __restrict__ out)
{
  __shared__ __align__(16) ushort Ks[64][128];    // K tile  [s][h]
  __shared__ __align__(16) ushort Vs[128][64];    // V tile  [h][s] (pre-transposed)
  __shared__ __align__(16) ushort Ps[4][16][64];  // per-wave P round-trip
  const int tid  = threadIdx.x;
  const int lane = tid & 63, wave = tid >> 6;
  const int l15  = lane & 15, l4 = lane >> 4;
  const int blk  = blockIdx.x;
  const int b = blk >> 5, qi = blk & 31;
  const int q0 = qi * 64;
  const size_t mbase = (size_t)b * T_ + q0;

  // Q fragments (A-layout: row = lane&15, k = (lane>>4)*8+j), direct from global
  bf16x8 qa[4];
  {
    const ushort* qrow = &qh[(mbase + wave * 16 + l15) * H_];
    #pragma unroll
    for (int kc = 0; kc < 4; ++kc)
      qa[kc] = *reinterpret_cast<const bf16x8*>(&qrow[kc * 32 + l4 * 8]);
  }

  f32x4 o[8];
  #pragma unroll
  for (int i = 0; i < 8; ++i) o[i] = f32x4{0.f, 0.f, 0.f, 0.f};
  float mrow[4] = {-1e9f, -1e9f, -1e9f, -1e9f};
  float lrow[4] = {0.f, 0.f, 0.f, 0.f};

  const int nt = qi + 1;
  for (int kt = 0; kt < nt; ++kt) {
    const int kv0 = kt * 64;
    __syncthreads();
    // stage K tile (coalesced 16B)
    for (int i = tid; i < 1024; i += 256) {
      const int r = i >> 4, c8 = i & 15;
      *reinterpret_cast<bf16x8*>(&Ks[r][c8 * 8]) =
          *reinterpret_cast<const bf16x8*>(
              &kh[((size_t)b * T_ + kv0 + r) * H_ + c8 * 8]);
    }
    // stage Vt tile (coalesced 16B)
    for (int i = tid; i < 1024; i += 256) {
      const int r = i >> 3, c8 = i & 7;
      *reinterpret_cast<bf16x8*>(&Vs[r][c8 * 8]) =
          *reinterpret_cast<const bf16x8*>(
              &vt[((size_t)b * H_ + r) * T_ + kv0 + c8 * 8]);
    }
    __syncthreads();

    // S = Q K^T  (4 col-tiles of 16 keys)
    f32x4 s[4];
    #pragma unroll
    for (int ct = 0; ct < 4; ++ct) {
      s[ct] = f32x4{0.f, 0.f, 0.f, 0.f};
      #pragma unroll
      for (int kc = 0; kc < 4; ++kc) {
        bf16x8 kb = *reinterpret_cast<const bf16x8*>(
            &Ks[ct * 16 + l15][kc * 32 + l4 * 8]);
        s[ct] = __builtin_amdgcn_mfma_f32_16x16x32_bf16(qa[kc], kb, s[ct], 0, 0, 0);
      }
    }
    // scale + causal mask (only the diagonal tile needs it)
    const bool diag = (kv0 == q0);
    float sv[4][4];
    #pragma unroll
    for (int ct = 0; ct < 4; ++ct)
      #pragma unroll
      for (int reg = 0; reg < 4; ++reg) {
        float v = s[ct][reg] * SCALE;
        if (diag) {
          const int sg = kv0 + ct * 16 + l15;
          const int rg = q0 + wave * 16 + l4 * 4 + reg;
          if (sg > rg) v = -1e9f;
        }
        sv[ct][reg] = v;
      }
    // online softmax: row r lives in lanes (l>>4)==r>>2, reg=r&3, across 16 cols
    float mnew[4], alpha[4], ls[4];
    #pragma unroll
    for (int reg = 0; reg < 4; ++reg) {
      float m = fmaxf(fmaxf(sv[0][reg], sv[1][reg]), fmaxf(sv[2][reg], sv[3][reg]));
      #pragma unroll
      for (int msk = 1; msk < 16; msk <<= 1) m = fmaxf(m, __shfl_xor(m, msk));
      mnew[reg]  = fmaxf(mrow[reg], m);
      alpha[reg] = __expf(mrow[reg] - mnew[reg]);
      ls[reg] = 0.f;
    }
    #pragma unroll
    for (int ct = 0; ct < 4; ++ct)
      #pragma unroll
      for (int reg = 0; reg < 4; ++reg) {
        const float p = __expf(sv[ct][reg] - mnew[reg]);
        ls[reg] += p;
        Ps[wave][l4 * 4 + reg][ct * 16 + l15] = f2bf(p);
      }
    #pragma unroll
    for (int reg = 0; reg < 4; ++reg) {
      float t = ls[reg];
      #pragma unroll
      for (int msk = 1; msk < 16; msk <<= 1) t += __shfl_xor(t, msk);
      lrow[reg] = lrow[reg] * alpha[reg] + t;
      mrow[reg] = mnew[reg];
    }
    // rescale O
    #pragma unroll
    for (int ct = 0; ct < 8; ++ct)
      #pragma unroll
      for (int reg = 0; reg < 4; ++reg) o[ct][reg] *= alpha[reg];
    __syncthreads();   // make Ps visible (uniform trip count across waves)
    // O += P V   (P A-frags from LDS round-trip, V B-frags from transposed tile)
    bf16x8 pa[2];
    #pragma unroll
    for (int kc = 0; kc < 2; ++kc)
      pa[kc] = *reinterpret_cast<const bf16x8*>(&Ps[wave][l15][kc * 32 + l4 * 8]);
    #pragma unroll
    for (int ct = 0; ct < 8; ++ct) {
      #pragma unroll
      for (int kc = 0; kc < 2; ++kc) {
        bf16x8 vb = *reinterpret_cast<const bf16x8*>(
            &Vs[ct * 16 + l15][kc * 32 + l4 * 8]);
        o[ct] = __builtin_amdgcn_mfma_f32_16x16x32_bf16(pa[kc], vb, o[ct], 0, 0, 0);
      }
    }
  }
  // epilogue: divide by softmax denominator, write fp32
  #pragma unroll
  for (int ct = 0; ct < 8; ++ct)
    #pragma unroll
    for (int reg = 0; reg < 4; ++reg) {
      const size_t row = mbase + wave * 16 + l4 * 4 + reg;
      out[row * H_ + ct * 16 + l15] = o[ct][reg] / lrow[reg];
    }
}

extern "C" void kernel_launch(void* const* d_in, const int* in_sizes, int n_in,
                              void* d_out, int out_size, void* d_ws, size_t ws_size,
                              hipStream_t stream) {
  const float* x  = (const float*)d_in[0];
  const float* Wq = (const float*)d_in[1];
  const float* Wk = (const float*)d_in[2];
  const float* Wv = (const float*)d_in[3];
  float* out = (float*)d_out;
  ushort* qh = (ushort*)d_ws;                       // [BT][128] bf16
  ushort* kh = qh + (size_t)BT * H_;                // [BT][128] bf16
  ushort* vt = kh + (size_t)BT * H_;                // [B][128][T] bf16
  proj_kernel<<<256, 256, 0, stream>>>(x, Wq, Wk, Wv, qh, kh, vt);
  attn_kernel<<<256, 256, 0, stream>>>(qh, kh, vt, out);
}

// Round 2
// 198.962 us; speedup vs baseline: 2.8900x; 2.8900x over previous
//
#include <hip/hip_runtime.h>
#include <hip/hip_bf16.h>
#include <stdint.h>

#define B_ 8
#define T_ 2048
#define C_ 1024
#define H_ 128
#define BT (B_*T_)
#define SCALE 0.08838834764831845f

typedef __attribute__((ext_vector_type(8))) short bf16x8;
typedef __attribute__((ext_vector_type(4))) float f32x4;

__device__ __forceinline__ ushort f2bf(float f) {
  union { float f; uint32_t u; } un; un.f = f;
  return (ushort)((un.u + 0x7fffu + ((un.u >> 16) & 1u)) >> 16);
}

// ---------------- prep: W -> W^T bf16  (wt [384][1024], rows: 0-127 Wq cols,
// 128-255 Wk cols, 256-383 Wv cols) ----------------
__global__ __launch_bounds__(256) void wtrans_kernel(
    const float* __restrict__ Wq, const float* __restrict__ Wk,
    const float* __restrict__ Wv, ushort* __restrict__ wt)
{
  const int tt = blockIdx.x * 256 + threadIdx.x;   // 0..24575
  const int n = tt >> 6;                            // 0..383
  const int k0 = (tt & 63) << 4;                    // 16 k's per thread
  const float* W = (n < 128) ? Wq : (n < 256 ? Wk : Wv);
  const int h = n & 127;
  ushort tmp[16];
  #pragma unroll
  for (int j = 0; j < 16; ++j)
    tmp[j] = f2bf(W[(size_t)(k0 + j) * H_ + h]);
  *reinterpret_cast<bf16x8*>(&wt[(size_t)n * C_ + k0]) =
      *reinterpret_cast<bf16x8*>(&tmp[0]);
  *reinterpret_cast<bf16x8*>(&wt[(size_t)n * C_ + k0 + 8]) =
      *reinterpret_cast<bf16x8*>(&tmp[8]);
}

// ---------------- proj: bf16 GEMM, m97 structure ----------------
// A = x (fp32, converted on stage) [16384][1024]; B^T = wt [384][1024].
// Block: 128 rows x 128 cols (one of 3 n-blocks), BK=64, 4 waves (2x2).
// nb==2 (V): operands swapped in MFMA -> computes v^T, written to vt[B][128][T].
__global__ __launch_bounds__(256) void proj_kernel(
    const float* __restrict__ x, const ushort* __restrict__ wt,
    ushort* __restrict__ qh, ushort* __restrict__ kh, ushort* __restrict__ vt)
{
  __shared__ __align__(16) ushort As[128][64];
  __shared__ __align__(16) ushort Bs[128][64];
  const int tid  = threadIdx.x;
  const int lane = tid & 63, wave = tid >> 6;
  const int l15  = lane & 15, l4 = lane >> 4;
  // bijective XCD swizzle: nwg=384, 48 per XCD -> mb-triplets co-XCD
  const int o  = (blockIdx.x & 7) * 48 + (blockIdx.x >> 3);
  const int mb = o / 3, nb = o - mb * 3;
  const int m0 = mb * 128, n0 = nb * 128;
  const int wr = wave >> 1, wc = wave & 1;

  f32x4 acc[4][4];
  #pragma unroll
  for (int i = 0; i < 4; ++i)
    #pragma unroll
    for (int j = 0; j < 4; ++j) acc[i][j] = f32x4{0.f, 0.f, 0.f, 0.f};

  for (int k0 = 0; k0 < C_; k0 += 64) {
    __syncthreads();
    // stage A: fp32 -> bf16, 8 float4 per thread
    #pragma unroll
    for (int it = 0; it < 8; ++it) {
      const int f4 = it * 256 + tid;        // 0..2047
      const int r = f4 >> 4, c4 = f4 & 15;
      float4 v = *reinterpret_cast<const float4*>(
          &x[(size_t)(m0 + r) * C_ + k0 + 4 * c4]);
      ushort4 pk;
      pk.x = f2bf(v.x); pk.y = f2bf(v.y); pk.z = f2bf(v.z); pk.w = f2bf(v.w);
      *reinterpret_cast<ushort4*>(&As[r][4 * c4]) = pk;
    }
    // stage B: bf16x8 copy, 4 per thread
    #pragma unroll
    for (int it = 0; it < 4; ++it) {
      const int f8 = it * 256 + tid;        // 0..1023
      const int r = f8 >> 3, c8 = f8 & 7;
      *reinterpret_cast<bf16x8*>(&Bs[r][c8 * 8]) =
          *reinterpret_cast<const bf16x8*>(
              &wt[(size_t)(n0 + r) * C_ + k0 + c8 * 8]);
    }
    __syncthreads();

    bf16x8 a[4][2], b[4][2];
    #pragma unroll
    for (int mi = 0; mi < 4; ++mi)
      #pragma unroll
      for (int kc = 0; kc < 2; ++kc)
        a[mi][kc] = *reinterpret_cast<const bf16x8*>(
            &As[wr * 64 + mi * 16 + l15][kc * 32 + l4 * 8]);
    #pragma unroll
    for (int ni = 0; ni < 4; ++ni)
      #pragma unroll
      for (int kc = 0; kc < 2; ++kc)
        b[ni][kc] = *reinterpret_cast<const bf16x8*>(
            &Bs[wc * 64 + ni * 16 + l15][kc * 32 + l4 * 8]);

    __builtin_amdgcn_s_setprio(1);
    if (nb != 2) {
      #pragma unroll
      for (int mi = 0; mi < 4; ++mi)
        #pragma unroll
        for (int ni = 0; ni < 4; ++ni)
          #pragma unroll
          for (int kc = 0; kc < 2; ++kc)
            acc[mi][ni] = __builtin_amdgcn_mfma_f32_16x16x32_bf16(
                a[mi][kc], b[ni][kc], acc[mi][ni], 0, 0, 0);
    } else {
      // swapped: D = wt_rows x x_rows = v^T
      #pragma unroll
      for (int mi = 0; mi < 4; ++mi)
        #pragma unroll
        for (int ni = 0; ni < 4; ++ni)
          #pragma unroll
          for (int kc = 0; kc < 2; ++kc)
            acc[mi][ni] = __builtin_amdgcn_mfma_f32_16x16x32_bf16(
                b[ni][kc], a[mi][kc], acc[mi][ni], 0, 0, 0);
    }
    __builtin_amdgcn_s_setprio(0);
  }

  // epilogue (C/D layout: col=lane&15, row=(lane>>4)*4+reg)
  if (nb != 2) {
    ushort* dst = (nb == 0) ? qh : kh;
    #pragma unroll
    for (int mi = 0; mi < 4; ++mi)
      #pragma unroll
      for (int ni = 0; ni < 4; ++ni)
        #pragma unroll
        for (int reg = 0; reg < 4; ++reg) {
          const int row = m0 + wr * 64 + mi * 16 + l4 * 4 + reg;
          const int col = wc * 64 + ni * 16 + l15;
          dst[(size_t)row * H_ + col] = f2bf(acc[mi][ni][reg]);
        }
  } else {
    const int b = m0 >> 11, t0 = (m0 & 2047);
    #pragma unroll
    for (int mi = 0; mi < 4; ++mi)
      #pragma unroll
      for (int ni = 0; ni < 4; ++ni)
        #pragma unroll
        for (int reg = 0; reg < 4; ++reg) {
          const int h = wc * 64 + ni * 16 + l4 * 4 + reg;   // D row
          const int t = t0 + wr * 64 + mi * 16 + l15;       // D col
          vt[((size_t)b * H_ + h) * T_ + t] = f2bf(acc[mi][ni][reg]);
        }
  }
}

// ---------------- flash attention (causal) ----------------
// 1 block = 64 query rows of one batch; 4 waves x 16 rows each.
// All LDS tiles XOR-swizzled at 16B granularity: chunk' = chunk ^ (row&7).
__global__ __launch_bounds__(256) void attn_kernel(
    const ushort* __restrict__ qh, const ushort* __restrict__ kh,
    const ushort* __restrict__ vt, float* __restrict__ out)
{
  __shared__ __align__(16) ushort Ks[64][128];    // [s][h], swizzled
  __shared__ __align__(16) ushort Vs[128][64];    // [h][s], swizzled
  __shared__ __align__(16) ushort Ps[4][16][64];  // per-wave P, swizzled
  const int tid  = threadIdx.x;
  const int lane = tid & 63, wave = tid >> 6;
  const int l15  = lane & 15, l4 = lane >> 4;
  // XCD swizzle: one batch per XCD (32 blocks each)
  const int o = (blockIdx.x & 7) * 32 + (blockIdx.x >> 3);
  const int b = o >> 5, qi = o & 31;
  const int q0 = qi * 64;
  const size_t mbase = (size_t)b * T_ + q0;
  const int swz = l15 & 7;                        // row&7 of fragment reads

  bf16x8 qa[4];
  {
    const ushort* qrow = &qh[(mbase + wave * 16 + l15) * H_];
    #pragma unroll
    for (int kc = 0; kc < 4; ++kc)
      qa[kc] = *reinterpret_cast<const bf16x8*>(&qrow[kc * 32 + l4 * 8]);
  }

  f32x4 o_[8];
  #pragma unroll
  for (int i = 0; i < 8; ++i) o_[i] = f32x4{0.f, 0.f, 0.f, 0.f};
  float mrow[4] = {-1e9f, -1e9f, -1e9f, -1e9f};
  float lrow[4] = {0.f, 0.f, 0.f, 0.f};

  const int nt = qi + 1;
  for (int kt = 0; kt < nt; ++kt) {
    const int kv0 = kt * 64;
    __syncthreads();
    // stage K tile (16 chunks/row of 16B, swizzled)
    for (int i = tid; i < 1024; i += 256) {
      const int r = i >> 4, c8 = i & 15;
      const int c8s = (c8 & 7) ^ (r & 7);
      *reinterpret_cast<bf16x8*>(&Ks[r][((c8 & 8) | c8s) * 8]) =
          *reinterpret_cast<const bf16x8*>(
              &kh[((size_t)b * T_ + kv0 + r) * H_ + c8 * 8]);
    }
    // stage Vt tile (8 chunks/row, swizzled)
    for (int i = tid; i < 1024; i += 256) {
      const int r = i >> 3, c8 = i & 7;
      const int c8s = c8 ^ (r & 7);
      *reinterpret_cast<bf16x8*>(&Vs[r][c8s * 8]) =
          *reinterpret_cast<const bf16x8*>(
              &vt[((size_t)b * H_ + r) * T_ + kv0 + c8 * 8]);
    }
    __syncthreads();

    // S = Q K^T
    f32x4 s[4];
    __builtin_amdgcn_s_setprio(1);
    #pragma unroll
    for (int ct = 0; ct < 4; ++ct) {
      s[ct] = f32x4{0.f, 0.f, 0.f, 0.f};
      #pragma unroll
      for (int kc = 0; kc < 4; ++kc) {
        const int chunk = ((kc * 4 + l4) & 7) ^ swz;   // within-128B swizzle
        bf16x8 kb = *reinterpret_cast<const bf16x8*>(
            &Ks[ct * 16 + l15][(((kc * 4 + l4) & 8) | chunk) * 8]);
        s[ct] = __builtin_amdgcn_mfma_f32_16x16x32_bf16(qa[kc], kb, s[ct], 0, 0, 0);
      }
    }
    __builtin_amdgcn_s_setprio(0);

    const bool diag = (kv0 == q0);
    float sv[4][4];
    #pragma unroll
    for (int ct = 0; ct < 4; ++ct)
      #pragma unroll
      for (int reg = 0; reg < 4; ++reg) {
        float v = s[ct][reg] * SCALE;
        if (diag) {
          const int sg = kv0 + ct * 16 + l15;
          const int rg = q0 + wave * 16 + l4 * 4 + reg;
          if (sg > rg) v = -1e9f;
        }
        sv[ct][reg] = v;
      }
    float mnew[4], alpha[4], ls[4];
    #pragma unroll
    for (int reg = 0; reg < 4; ++reg) {
      float m = fmaxf(fmaxf(sv[0][reg], sv[1][reg]), fmaxf(sv[2][reg], sv[3][reg]));
      #pragma unroll
      for (int msk = 1; msk < 16; msk <<= 1) m = fmaxf(m, __shfl_xor(m, msk));
      mnew[reg]  = fmaxf(mrow[reg], m);
      alpha[reg] = __expf(mrow[reg] - mnew[reg]);
      ls[reg] = 0.f;
    }
    #pragma unroll
    for (int ct = 0; ct < 4; ++ct)
      #pragma unroll
      for (int reg = 0; reg < 4; ++reg) {
        const float p = __expf(sv[ct][reg] - mnew[reg]);
        ls[reg] += p;
        const int prow = l4 * 4 + reg;
        Ps[wave][prow][(ct * 16 + l15) ^ ((prow & 7) * 8)] = f2bf(p);
      }
    #pragma unroll
    for (int reg = 0; reg < 4; ++reg) {
      float t = ls[reg];
      #pragma unroll
      for (int msk = 1; msk < 16; msk <<= 1) t += __shfl_xor(t, msk);
      lrow[reg] = lrow[reg] * alpha[reg] + t;
      mrow[reg] = mnew[reg];
    }
    #pragma unroll
    for (int ct = 0; ct < 8; ++ct)
      #pragma unroll
      for (int reg = 0; reg < 4; ++reg) o_[ct][reg] *= alpha[reg];
    __syncthreads();
    // O += P V
    bf16x8 pa[2];
    #pragma unroll
    for (int kc = 0; kc < 2; ++kc)
      pa[kc] = *reinterpret_cast<const bf16x8*>(
          &Ps[wave][l15][((kc * 4 + l4) ^ swz) * 8]);
    __builtin_amdgcn_s_setprio(1);
    #pragma unroll
    for (int ct = 0; ct < 8; ++ct) {
      #pragma unroll
      for (int kc = 0; kc < 2; ++kc) {
        bf16x8 vb = *reinterpret_cast<const bf16x8*>(
            &Vs[ct * 16 + l15][((kc * 4 + l4) ^ swz) * 8]);
        o_[ct] = __builtin_amdgcn_mfma_f32_16x16x32_bf16(pa[kc], vb, o_[ct], 0, 0, 0);
      }
    }
    __builtin_amdgcn_s_setprio(0);
  }
  #pragma unroll
  for (int ct = 0; ct < 8; ++ct)
    #pragma unroll
    for (int reg = 0; reg < 4; ++reg) {
      const size_t row = mbase + wave * 16 + l4 * 4 + reg;
      out[row * H_ + ct * 16 + l15] = o_[ct][reg] / lrow[reg];
    }
}

extern "C" void kernel_launch(void* const* d_in, const int* in_sizes, int n_in,
                              void* d_out, int out_size, void* d_ws, size_t ws_size,
                              hipStream_t stream) {
  const float* x  = (const float*)d_in[0];
  const float* Wq = (const float*)d_in[1];
  const float* Wk = (const float*)d_in[2];
  const float* Wv = (const float*)d_in[3];
  float* out = (float*)d_out;
  ushort* qh = (ushort*)d_ws;                       // [16384][128] bf16
  ushort* kh = qh + (size_t)BT * H_;                // [16384][128] bf16
  ushort* vt = kh + (size_t)BT * H_;                // [8][128][2048] bf16
  ushort* wt = vt + (size_t)B_ * H_ * T_;           // [384][1024] bf16
  wtrans_kernel<<<96, 256, 0, stream>>>(Wq, Wk, Wv, wt);
  proj_kernel<<<384, 256, 0, stream>>>(x, wt, qh, kh, vt);
  attn_kernel<<<256, 256, 0, stream>>>(qh, kh, vt, out);
}

// Round 3
// 113.723 us; speedup vs baseline: 5.0562x; 1.7495x over previous
//
#include <hip/hip_runtime.h>
#include <hip/hip_bf16.h>
#include <stdint.h>

#define B_ 8
#define T_ 2048
#define C_ 1024
#define H_ 128
#define BT (B_*T_)
#define SCALE 0.08838834764831845f
#define CH 8   // KV tiles (of 64) per chunk-block

typedef __attribute__((ext_vector_type(8))) short bf16x8;
typedef __attribute__((ext_vector_type(4))) float f32x4;

__device__ __forceinline__ ushort f2bf(float f) {
  union { float f; uint32_t u; } un; un.f = f;
  return (ushort)((un.u + 0x7fffu + ((un.u >> 16) & 1u)) >> 16);
}
__device__ __forceinline__ float bf2f(ushort h) {
  union { uint32_t u; float f; } un; un.u = ((uint32_t)h) << 16;
  return un.f;
}

// ---------------- prep: W -> W^T bf16  (wt [384][1024]) ----------------
__global__ __launch_bounds__(256) void wtrans_kernel(
    const float* __restrict__ Wq, const float* __restrict__ Wk,
    const float* __restrict__ Wv, ushort* __restrict__ wt)
{
  const int tt = blockIdx.x * 256 + threadIdx.x;   // 0..24575
  const int n = tt >> 6;                            // 0..383
  const int k0 = (tt & 63) << 4;                    // 16 k's per thread
  const float* W = (n < 128) ? Wq : (n < 256 ? Wk : Wv);
  const int h = n & 127;
  ushort tmp[16];
  #pragma unroll
  for (int j = 0; j < 16; ++j)
    tmp[j] = f2bf(W[(size_t)(k0 + j) * H_ + h]);
  *reinterpret_cast<bf16x8*>(&wt[(size_t)n * C_ + k0]) =
      *reinterpret_cast<bf16x8*>(&tmp[0]);
  *reinterpret_cast<bf16x8*>(&wt[(size_t)n * C_ + k0 + 8]) =
      *reinterpret_cast<bf16x8*>(&tmp[8]);
}

// ---------------- proj: bf16 GEMM, m97 structure (unchanged) ----------------
__global__ __launch_bounds__(256) void proj_kernel(
    const float* __restrict__ x, const ushort* __restrict__ wt,
    ushort* __restrict__ qh, ushort* __restrict__ kh, ushort* __restrict__ vt)
{
  __shared__ __align__(16) ushort As[128][64];
  __shared__ __align__(16) ushort Bs[128][64];
  const int tid  = threadIdx.x;
  const int lane = tid & 63, wave = tid >> 6;
  const int l15  = lane & 15, l4 = lane >> 4;
  const int o  = (blockIdx.x & 7) * 48 + (blockIdx.x >> 3);
  const int mb = o / 3, nb = o - mb * 3;
  const int m0 = mb * 128, n0 = nb * 128;
  const int wr = wave >> 1, wc = wave & 1;

  f32x4 acc[4][4];
  #pragma unroll
  for (int i = 0; i < 4; ++i)
    #pragma unroll
    for (int j = 0; j < 4; ++j) acc[i][j] = f32x4{0.f, 0.f, 0.f, 0.f};

  for (int k0 = 0; k0 < C_; k0 += 64) {
    __syncthreads();
    #pragma unroll
    for (int it = 0; it < 8; ++it) {
      const int f4 = it * 256 + tid;
      const int r = f4 >> 4, c4 = f4 & 15;
      float4 v = *reinterpret_cast<const float4*>(
          &x[(size_t)(m0 + r) * C_ + k0 + 4 * c4]);
      ushort4 pk;
      pk.x = f2bf(v.x); pk.y = f2bf(v.y); pk.z = f2bf(v.z); pk.w = f2bf(v.w);
      *reinterpret_cast<ushort4*>(&As[r][4 * c4]) = pk;
    }
    #pragma unroll
    for (int it = 0; it < 4; ++it) {
      const int f8 = it * 256 + tid;
      const int r = f8 >> 3, c8 = f8 & 7;
      *reinterpret_cast<bf16x8*>(&Bs[r][c8 * 8]) =
          *reinterpret_cast<const bf16x8*>(
              &wt[(size_t)(n0 + r) * C_ + k0 + c8 * 8]);
    }
    __syncthreads();

    bf16x8 a[4][2], b[4][2];
    #pragma unroll
    for (int mi = 0; mi < 4; ++mi)
      #pragma unroll
      for (int kc = 0; kc < 2; ++kc)
        a[mi][kc] = *reinterpret_cast<const bf16x8*>(
            &As[wr * 64 + mi * 16 + l15][kc * 32 + l4 * 8]);
    #pragma unroll
    for (int ni = 0; ni < 4; ++ni)
      #pragma unroll
      for (int kc = 0; kc < 2; ++kc)
        b[ni][kc] = *reinterpret_cast<const bf16x8*>(
            &Bs[wc * 64 + ni * 16 + l15][kc * 32 + l4 * 8]);

    __builtin_amdgcn_s_setprio(1);
    if (nb != 2) {
      #pragma unroll
      for (int mi = 0; mi < 4; ++mi)
        #pragma unroll
        for (int ni = 0; ni < 4; ++ni)
          #pragma unroll
          for (int kc = 0; kc < 2; ++kc)
            acc[mi][ni] = __builtin_amdgcn_mfma_f32_16x16x32_bf16(
                a[mi][kc], b[ni][kc], acc[mi][ni], 0, 0, 0);
    } else {
      #pragma unroll
      for (int mi = 0; mi < 4; ++mi)
        #pragma unroll
        for (int ni = 0; ni < 4; ++ni)
          #pragma unroll
          for (int kc = 0; kc < 2; ++kc)
            acc[mi][ni] = __builtin_amdgcn_mfma_f32_16x16x32_bf16(
                b[ni][kc], a[mi][kc], acc[mi][ni], 0, 0, 0);
    }
    __builtin_amdgcn_s_setprio(0);
  }

  if (nb != 2) {
    ushort* dst = (nb == 0) ? qh : kh;
    #pragma unroll
    for (int mi = 0; mi < 4; ++mi)
      #pragma unroll
      for (int ni = 0; ni < 4; ++ni)
        #pragma unroll
        for (int reg = 0; reg < 4; ++reg) {
          const int row = m0 + wr * 64 + mi * 16 + l4 * 4 + reg;
          const int col = wc * 64 + ni * 16 + l15;
          dst[(size_t)row * H_ + col] = f2bf(acc[mi][ni][reg]);
        }
  } else {
    const int b = m0 >> 11, t0 = (m0 & 2047);
    #pragma unroll
    for (int mi = 0; mi < 4; ++mi)
      #pragma unroll
      for (int ni = 0; ni < 4; ++ni)
        #pragma unroll
        for (int reg = 0; reg < 4; ++reg) {
          const int h = wc * 64 + ni * 16 + l4 * 4 + reg;
          const int t = t0 + wr * 64 + mi * 16 + l15;
          vt[((size_t)b * H_ + h) * T_ + t] = f2bf(acc[mi][ni][reg]);
        }
  }
}

// ---------------- flash attention, KV-split (flash-decode style) ----------
// One block = 64 q-rows of one (b,qi), KV-chunk of <=8 tiles (512 keys).
// qi<=7: single chunk -> write out directly. Else write unnormalized
// partials (bf16 O', fp32 m,l) merged by combine_kernel.
__global__ __launch_bounds__(256) void attn_kernel(
    const ushort* __restrict__ qh, const ushort* __restrict__ kh,
    const ushort* __restrict__ vt, ushort* __restrict__ pO,
    float* __restrict__ pm, float* __restrict__ pl, float* __restrict__ out)
{
  __shared__ __align__(16) ushort Ks[64][128];    // [s][h], swizzled
  __shared__ __align__(16) ushort Vs[128][64];    // [h][s], swizzled
  __shared__ __align__(16) ushort Ps[4][16][64];  // per-wave P, swizzled
  const int tid  = threadIdx.x;
  const int lane = tid & 63, wave = tid >> 6;
  const int l15  = lane & 15, l4 = lane >> 4;
  // 640 blocks; XCD swizzle: batch b == XCD (80 chunk-blocks per batch)
  const int o = (blockIdx.x & 7) * 80 + (blockIdx.x >> 3);
  const int b = o / 80, u = o % 80;
  int g = 0;
  if (u >= 8)  g = 1;
  if (u >= 24) g = 2;
  if (u >= 48) g = 3;
  const int gp1 = g + 1;
  const int u2 = u - 4 * g * gp1;
  const int qi = 8 * g + u2 / gp1;
  const int ci = u2 % gp1;
  const int nchunk = gp1;
  const int q0 = qi * 64;
  const int kt0 = ci * CH;
  const int kt1 = min(qi + 1, kt0 + CH);
  const size_t mbase = (size_t)b * T_ + q0;
  const int swz = l15 & 7;

  bf16x8 qa[4];
  {
    const ushort* qrow = &qh[(mbase + wave * 16 + l15) * H_];
    #pragma unroll
    for (int kc = 0; kc < 4; ++kc)
      qa[kc] = *reinterpret_cast<const bf16x8*>(&qrow[kc * 32 + l4 * 8]);
  }

  f32x4 o_[8];
  #pragma unroll
  for (int i = 0; i < 8; ++i) o_[i] = f32x4{0.f, 0.f, 0.f, 0.f};
  float mrow[4] = {-1e9f, -1e9f, -1e9f, -1e9f};
  float lrow[4] = {0.f, 0.f, 0.f, 0.f};

  for (int kt = kt0; kt < kt1; ++kt) {
    const int kv0 = kt * 64;
    __syncthreads();
    for (int i = tid; i < 1024; i += 256) {
      const int r = i >> 4, c8 = i & 15;
      const int c8s = (c8 & 7) ^ (r & 7);
      *reinterpret_cast<bf16x8*>(&Ks[r][((c8 & 8) | c8s) * 8]) =
          *reinterpret_cast<const bf16x8*>(
              &kh[((size_t)b * T_ + kv0 + r) * H_ + c8 * 8]);
    }
    for (int i = tid; i < 1024; i += 256) {
      const int r = i >> 3, c8 = i & 7;
      const int c8s = c8 ^ (r & 7);
      *reinterpret_cast<bf16x8*>(&Vs[r][c8s * 8]) =
          *reinterpret_cast<const bf16x8*>(
              &vt[((size_t)b * H_ + r) * T_ + kv0 + c8 * 8]);
    }
    __syncthreads();

    // S = Q K^T
    f32x4 s[4];
    __builtin_amdgcn_s_setprio(1);
    #pragma unroll
    for (int ct = 0; ct < 4; ++ct) {
      s[ct] = f32x4{0.f, 0.f, 0.f, 0.f};
      #pragma unroll
      for (int kc = 0; kc < 4; ++kc) {
        const int chunk = ((kc * 4 + l4) & 7) ^ swz;
        bf16x8 kb = *reinterpret_cast<const bf16x8*>(
            &Ks[ct * 16 + l15][(((kc * 4 + l4) & 8) | chunk) * 8]);
        s[ct] = __builtin_amdgcn_mfma_f32_16x16x32_bf16(qa[kc], kb, s[ct], 0, 0, 0);
      }
    }
    __builtin_amdgcn_s_setprio(0);

    const bool diag = (kv0 == q0);
    float sv[4][4];
    #pragma unroll
    for (int ct = 0; ct < 4; ++ct)
      #pragma unroll
      for (int reg = 0; reg < 4; ++reg) {
        float v = s[ct][reg] * SCALE;
        if (diag) {
          const int sg = kv0 + ct * 16 + l15;
          const int rg = q0 + wave * 16 + l4 * 4 + reg;
          if (sg > rg) v = -1e9f;
        }
        sv[ct][reg] = v;
      }
    float mnew[4], alpha[4], ls[4];
    #pragma unroll
    for (int reg = 0; reg < 4; ++reg) {
      float m = fmaxf(fmaxf(sv[0][reg], sv[1][reg]), fmaxf(sv[2][reg], sv[3][reg]));
      #pragma unroll
      for (int msk = 1; msk < 16; msk <<= 1) m = fmaxf(m, __shfl_xor(m, msk));
      mnew[reg]  = fmaxf(mrow[reg], m);
      alpha[reg] = __expf(mrow[reg] - mnew[reg]);
      ls[reg] = 0.f;
    }
    #pragma unroll
    for (int ct = 0; ct < 4; ++ct)
      #pragma unroll
      for (int reg = 0; reg < 4; ++reg) {
        const float p = __expf(sv[ct][reg] - mnew[reg]);
        ls[reg] += p;
        const int prow = l4 * 4 + reg;
        Ps[wave][prow][(ct * 16 + l15) ^ ((prow & 7) * 8)] = f2bf(p);
      }
    #pragma unroll
    for (int reg = 0; reg < 4; ++reg) {
      float t = ls[reg];
      #pragma unroll
      for (int msk = 1; msk < 16; msk <<= 1) t += __shfl_xor(t, msk);
      lrow[reg] = lrow[reg] * alpha[reg] + t;
      mrow[reg] = mnew[reg];
    }
    #pragma unroll
    for (int ct = 0; ct < 8; ++ct)
      #pragma unroll
      for (int reg = 0; reg < 4; ++reg) o_[ct][reg] *= alpha[reg];
    // NOTE: no barrier needed here — Ps is wave-private, Vs fenced above.
    bf16x8 pa[2];
    #pragma unroll
    for (int kc = 0; kc < 2; ++kc)
      pa[kc] = *reinterpret_cast<const bf16x8*>(
          &Ps[wave][l15][((kc * 4 + l4) ^ swz) * 8]);
    __builtin_amdgcn_s_setprio(1);
    #pragma unroll
    for (int ct = 0; ct < 8; ++ct) {
      #pragma unroll
      for (int kc = 0; kc < 2; ++kc) {
        bf16x8 vb = *reinterpret_cast<const bf16x8*>(
            &Vs[ct * 16 + l15][((kc * 4 + l4) ^ swz) * 8]);
        o_[ct] = __builtin_amdgcn_mfma_f32_16x16x32_bf16(pa[kc], vb, o_[ct], 0, 0, 0);
      }
    }
    __builtin_amdgcn_s_setprio(0);
  }

  if (nchunk == 1) {
    #pragma unroll
    for (int ct = 0; ct < 8; ++ct)
      #pragma unroll
      for (int reg = 0; reg < 4; ++reg) {
        const size_t row = mbase + wave * 16 + l4 * 4 + reg;
        out[row * H_ + ct * 16 + l15] = o_[ct][reg] / lrow[reg];
      }
  } else {
    const size_t slot = ((size_t)(b * 32 + qi)) * 4 + ci;
    ushort* po = pO + slot * 64 * 128;
    #pragma unroll
    for (int ct = 0; ct < 8; ++ct)
      #pragma unroll
      for (int reg = 0; reg < 4; ++reg) {
        const int row = wave * 16 + l4 * 4 + reg;
        po[(size_t)row * 128 + ct * 16 + l15] = f2bf(o_[ct][reg]);
      }
    #pragma unroll
    for (int reg = 0; reg < 4; ++reg) {
      if (l15 == 0) {
        const int row = wave * 16 + l4 * 4 + reg;
        pm[slot * 64 + row] = mrow[reg];
        pl[slot * 64 + row] = lrow[reg];
      }
    }
  }
}

// ---------------- combine partials for qi >= 8 ----------------
__global__ __launch_bounds__(256) void combine_kernel(
    const ushort* __restrict__ pO, const float* __restrict__ pm,
    const float* __restrict__ pl, float* __restrict__ out)
{
  const int o = blockIdx.x;              // 0..191
  const int b = o / 24, qi = 8 + o % 24;
  const int nc = (qi >> 3) + 1;          // 2..4
  const int tid = threadIdx.x;
  const int row = tid >> 2, cg = tid & 3;
  const size_t slotbase = ((size_t)(b * 32 + qi)) * 4;

  float M = -1e30f;
  for (int ci = 0; ci < nc; ++ci)
    M = fmaxf(M, pm[(slotbase + ci) * 64 + row]);

  float L = 0.f;
  float acc[32];
  #pragma unroll
  for (int j = 0; j < 32; ++j) acc[j] = 0.f;
  for (int ci = 0; ci < nc; ++ci) {
    const float e = __expf(pm[(slotbase + ci) * 64 + row] - M);
    L += pl[(slotbase + ci) * 64 + row] * e;
    const ushort* src = pO + (slotbase + ci) * 8192 + (size_t)row * 128 + cg * 32;
    #pragma unroll
    for (int j4 = 0; j4 < 4; ++j4) {
      bf16x8 v = *reinterpret_cast<const bf16x8*>(&src[j4 * 8]);
      #pragma unroll
      for (int j = 0; j < 8; ++j)
        acc[j4 * 8 + j] += e * bf2f((ushort)v[j]);
    }
  }
  const float inv = 1.f / L;
  float* dst = out + ((size_t)b * T_ + qi * 64 + row) * H_ + cg * 32;
  #pragma unroll
  for (int j4 = 0; j4 < 8; ++j4) {
    float4 w;
    w.x = acc[j4 * 4 + 0] * inv; w.y = acc[j4 * 4 + 1] * inv;
    w.z = acc[j4 * 4 + 2] * inv; w.w = acc[j4 * 4 + 3] * inv;
    *reinterpret_cast<float4*>(&dst[j4 * 4]) = w;
  }
}

extern "C" void kernel_launch(void* const* d_in, const int* in_sizes, int n_in,
                              void* d_out, int out_size, void* d_ws, size_t ws_size,
                              hipStream_t stream) {
  const float* x  = (const float*)d_in[0];
  const float* Wq = (const float*)d_in[1];
  const float* Wk = (const float*)d_in[2];
  const float* Wv = (const float*)d_in[3];
  float* out = (float*)d_out;
  ushort* qh = (ushort*)d_ws;                         // [16384][128] bf16
  ushort* kh = qh + (size_t)BT * H_;                  // [16384][128] bf16
  ushort* vt = kh + (size_t)BT * H_;                  // [8][128][2048] bf16
  ushort* wt = vt + (size_t)B_ * H_ * T_;             // [384][1024] bf16
  ushort* pO = wt + (size_t)384 * C_;                 // [8*32*4][64][128] bf16
  float*  pm = (float*)(pO + (size_t)8 * 32 * 4 * 64 * 128);  // [8*32*4][64]
  float*  pl = pm + (size_t)8 * 32 * 4 * 64;
  wtrans_kernel<<<96, 256, 0, stream>>>(Wq, Wk, Wv, wt);
  proj_kernel<<<384, 256, 0, stream>>>(x, wt, qh, kh, vt);
  attn_kernel<<<640, 256, 0, stream>>>(qh, kh, vt, pO, pm, pl, out);
  combine_kernel<<<192, 256, 0, stream>>>(pO, pm, pl, out);
}

// Round 4
// 79.773 us; speedup vs baseline: 7.2080x; 1.4256x over previous
//
#include <hip/hip_runtime.h>
#include <hip/hip_bf16.h>
#include <stdint.h>

#define B_ 8
#define T_ 2048
#define C_ 1024
#define H_ 128
#define BT (B_*T_)
#define SCALE 0.08838834764831845f
#define CH 8   // KV tiles (of 64) per chunk-block

typedef __attribute__((ext_vector_type(8))) short bf16x8;
typedef __attribute__((ext_vector_type(4))) float f32x4;

__device__ __forceinline__ ushort f2bf(float f) {
  union { float f; uint32_t u; } un; un.f = f;
  return (ushort)((un.u + 0x7fffu + ((un.u >> 16) & 1u)) >> 16);
}
__device__ __forceinline__ float bf2f(ushort h) {
  union { uint32_t u; float f; } un; un.u = ((uint32_t)h) << 16;
  return un.f;
}

// ---------------- prep: W -> W^T bf16  (wt [384][1024]) ----------------
__global__ __launch_bounds__(256) void wtrans_kernel(
    const float* __restrict__ Wq, const float* __restrict__ Wk,
    const float* __restrict__ Wv, ushort* __restrict__ wt)
{
  const int tt = blockIdx.x * 256 + threadIdx.x;   // 0..24575
  const int n = tt >> 6;                            // 0..383
  const int k0 = (tt & 63) << 4;                    // 16 k's per thread
  const float* W = (n < 128) ? Wq : (n < 256 ? Wk : Wv);
  const int h = n & 127;
  ushort tmp[16];
  #pragma unroll
  for (int j = 0; j < 16; ++j)
    tmp[j] = f2bf(W[(size_t)(k0 + j) * H_ + h]);
  *reinterpret_cast<bf16x8*>(&wt[(size_t)n * C_ + k0]) =
      *reinterpret_cast<bf16x8*>(&tmp[0]);
  *reinterpret_cast<bf16x8*>(&wt[(size_t)n * C_ + k0 + 8]) =
      *reinterpret_cast<bf16x8*>(&tmp[8]);
}

// ---------------- proj: bf16 GEMM, 64x128 tile, swizzled LDS -------------
// A = x (fp32->bf16 on stage) [16384][1024]; B^T = wt [384][1024].
// 768 blocks (= 3.0 blocks/CU), 4 waves (2x2), BK=64.
// nb==2 (V): swapped MFMA operands -> v^T, written to vt[B][128][T].
// All LDS 16B chunks XOR-swizzled: chunk' = chunk ^ (row&7)  (both sides).
__global__ __launch_bounds__(256, 3) void proj_kernel(
    const float* __restrict__ x, const ushort* __restrict__ wt,
    ushort* __restrict__ qh, ushort* __restrict__ kh, ushort* __restrict__ vt)
{
  __shared__ __align__(16) ushort As[64][64];
  __shared__ __align__(16) ushort Bs[128][64];
  const int tid  = threadIdx.x;
  const int lane = tid & 63, wave = tid >> 6;
  const int l15  = lane & 15, l4 = lane >> 4;
  // bijective XCD swizzle: nwg=768, 96/XCD -> 32 consecutive mb per XCD
  const int o  = (blockIdx.x & 7) * 96 + (blockIdx.x >> 3);
  const int mb = o / 3, nb = o - mb * 3;
  const int m0 = mb * 64, n0 = nb * 128;
  const int wr = wave >> 1, wc = wave & 1;

  f32x4 acc[2][4];
  #pragma unroll
  for (int i = 0; i < 2; ++i)
    #pragma unroll
    for (int j = 0; j < 4; ++j) acc[i][j] = f32x4{0.f, 0.f, 0.f, 0.f};

  for (int k0 = 0; k0 < C_; k0 += 64) {
    __syncthreads();
    // stage A: 64x64 fp32 -> bf16, 4 float4 per thread, swizzled 8B stores
    #pragma unroll
    for (int it = 0; it < 4; ++it) {
      const int f4 = it * 256 + tid;        // 0..1023
      const int r = f4 >> 4, c4 = f4 & 15;  // 16 float4 per row
      float4 v = *reinterpret_cast<const float4*>(
          &x[(size_t)(m0 + r) * C_ + k0 + 4 * c4]);
      ushort4 pk;
      pk.x = f2bf(v.x); pk.y = f2bf(v.y); pk.z = f2bf(v.z); pk.w = f2bf(v.w);
      const int ch = (c4 >> 1) ^ (r & 7);
      *reinterpret_cast<ushort4*>(&As[r][ch * 8 + (c4 & 1) * 4]) = pk;
    }
    // stage B: 128x64 bf16x8 copy, 4 per thread, swizzled 16B stores
    #pragma unroll
    for (int it = 0; it < 4; ++it) {
      const int f8 = it * 256 + tid;        // 0..1023
      const int r = f8 >> 3, c8 = f8 & 7;
      const int ch = c8 ^ (r & 7);
      *reinterpret_cast<bf16x8*>(&Bs[r][ch * 8]) =
          *reinterpret_cast<const bf16x8*>(
              &wt[(size_t)(n0 + r) * C_ + k0 + c8 * 8]);
    }
    __syncthreads();

    bf16x8 a[2][2], b[4][2];
    #pragma unroll
    for (int mi = 0; mi < 2; ++mi)
      #pragma unroll
      for (int kc = 0; kc < 2; ++kc) {
        const int row = wr * 32 + mi * 16 + l15;
        const int ch = (kc * 4 + l4) ^ (row & 7);
        a[mi][kc] = *reinterpret_cast<const bf16x8*>(&As[row][ch * 8]);
      }
    #pragma unroll
    for (int ni = 0; ni < 4; ++ni)
      #pragma unroll
      for (int kc = 0; kc < 2; ++kc) {
        const int row = wc * 64 + ni * 16 + l15;
        const int ch = (kc * 4 + l4) ^ (row & 7);
        b[ni][kc] = *reinterpret_cast<const bf16x8*>(&Bs[row][ch * 8]);
      }

    __builtin_amdgcn_s_setprio(1);
    if (nb != 2) {
      #pragma unroll
      for (int mi = 0; mi < 2; ++mi)
        #pragma unroll
        for (int ni = 0; ni < 4; ++ni)
          #pragma unroll
          for (int kc = 0; kc < 2; ++kc)
            acc[mi][ni] = __builtin_amdgcn_mfma_f32_16x16x32_bf16(
                a[mi][kc], b[ni][kc], acc[mi][ni], 0, 0, 0);
    } else {
      #pragma unroll
      for (int mi = 0; mi < 2; ++mi)
        #pragma unroll
        for (int ni = 0; ni < 4; ++ni)
          #pragma unroll
          for (int kc = 0; kc < 2; ++kc)
            acc[mi][ni] = __builtin_amdgcn_mfma_f32_16x16x32_bf16(
                b[ni][kc], a[mi][kc], acc[mi][ni], 0, 0, 0);
    }
    __builtin_amdgcn_s_setprio(0);
  }

  if (nb != 2) {
    ushort* dst = (nb == 0) ? qh : kh;
    #pragma unroll
    for (int mi = 0; mi < 2; ++mi)
      #pragma unroll
      for (int ni = 0; ni < 4; ++ni)
        #pragma unroll
        for (int reg = 0; reg < 4; ++reg) {
          const int row = m0 + wr * 32 + mi * 16 + l4 * 4 + reg;
          const int col = wc * 64 + ni * 16 + l15;
          dst[(size_t)row * H_ + col] = f2bf(acc[mi][ni][reg]);
        }
  } else {
    #pragma unroll
    for (int mi = 0; mi < 2; ++mi)
      #pragma unroll
      for (int ni = 0; ni < 4; ++ni)
        #pragma unroll
        for (int reg = 0; reg < 4; ++reg) {
          const int h = wc * 64 + ni * 16 + l4 * 4 + reg;     // D row
          const int gr = m0 + wr * 32 + mi * 16 + l15;        // global x row
          const int b = gr >> 11, t = gr & 2047;
          vt[((size_t)b * H_ + h) * T_ + t] = f2bf(acc[mi][ni][reg]);
        }
  }
}

// ---------------- flash attention, KV-split (unchanged from R3) ----------
__global__ __launch_bounds__(256) void attn_kernel(
    const ushort* __restrict__ qh, const ushort* __restrict__ kh,
    const ushort* __restrict__ vt, ushort* __restrict__ pO,
    float* __restrict__ pm, float* __restrict__ pl, float* __restrict__ out)
{
  __shared__ __align__(16) ushort Ks[64][128];    // [s][h], swizzled
  __shared__ __align__(16) ushort Vs[128][64];    // [h][s], swizzled
  __shared__ __align__(16) ushort Ps[4][16][64];  // per-wave P, swizzled
  const int tid  = threadIdx.x;
  const int lane = tid & 63, wave = tid >> 6;
  const int l15  = lane & 15, l4 = lane >> 4;
  const int o = (blockIdx.x & 7) * 80 + (blockIdx.x >> 3);
  const int b = o / 80, u = o % 80;
  int g = 0;
  if (u >= 8)  g = 1;
  if (u >= 24) g = 2;
  if (u >= 48) g = 3;
  const int gp1 = g + 1;
  const int u2 = u - 4 * g * gp1;
  const int qi = 8 * g + u2 / gp1;
  const int ci = u2 % gp1;
  const int nchunk = gp1;
  const int q0 = qi * 64;
  const int kt0 = ci * CH;
  const int kt1 = min(qi + 1, kt0 + CH);
  const size_t mbase = (size_t)b * T_ + q0;
  const int swz = l15 & 7;

  bf16x8 qa[4];
  {
    const ushort* qrow = &qh[(mbase + wave * 16 + l15) * H_];
    #pragma unroll
    for (int kc = 0; kc < 4; ++kc)
      qa[kc] = *reinterpret_cast<const bf16x8*>(&qrow[kc * 32 + l4 * 8]);
  }

  f32x4 o_[8];
  #pragma unroll
  for (int i = 0; i < 8; ++i) o_[i] = f32x4{0.f, 0.f, 0.f, 0.f};
  float mrow[4] = {-1e9f, -1e9f, -1e9f, -1e9f};
  float lrow[4] = {0.f, 0.f, 0.f, 0.f};

  for (int kt = kt0; kt < kt1; ++kt) {
    const int kv0 = kt * 64;
    __syncthreads();
    for (int i = tid; i < 1024; i += 256) {
      const int r = i >> 4, c8 = i & 15;
      const int c8s = (c8 & 7) ^ (r & 7);
      *reinterpret_cast<bf16x8*>(&Ks[r][((c8 & 8) | c8s) * 8]) =
          *reinterpret_cast<const bf16x8*>(
              &kh[((size_t)b * T_ + kv0 + r) * H_ + c8 * 8]);
    }
    for (int i = tid; i < 1024; i += 256) {
      const int r = i >> 3, c8 = i & 7;
      const int c8s = c8 ^ (r & 7);
      *reinterpret_cast<bf16x8*>(&Vs[r][c8s * 8]) =
          *reinterpret_cast<const bf16x8*>(
              &vt[((size_t)b * H_ + r) * T_ + kv0 + c8 * 8]);
    }
    __syncthreads();

    f32x4 s[4];
    __builtin_amdgcn_s_setprio(1);
    #pragma unroll
    for (int ct = 0; ct < 4; ++ct) {
      s[ct] = f32x4{0.f, 0.f, 0.f, 0.f};
      #pragma unroll
      for (int kc = 0; kc < 4; ++kc) {
        const int chunk = ((kc * 4 + l4) & 7) ^ swz;
        bf16x8 kb = *reinterpret_cast<const bf16x8*>(
            &Ks[ct * 16 + l15][(((kc * 4 + l4) & 8) | chunk) * 8]);
        s[ct] = __builtin_amdgcn_mfma_f32_16x16x32_bf16(qa[kc], kb, s[ct], 0, 0, 0);
      }
    }
    __builtin_amdgcn_s_setprio(0);

    const bool diag = (kv0 == q0);
    float sv[4][4];
    #pragma unroll
    for (int ct = 0; ct < 4; ++ct)
      #pragma unroll
      for (int reg = 0; reg < 4; ++reg) {
        float v = s[ct][reg] * SCALE;
        if (diag) {
          const int sg = kv0 + ct * 16 + l15;
          const int rg = q0 + wave * 16 + l4 * 4 + reg;
          if (sg > rg) v = -1e9f;
        }
        sv[ct][reg] = v;
      }
    float mnew[4], alpha[4], ls[4];
    #pragma unroll
    for (int reg = 0; reg < 4; ++reg) {
      float m = fmaxf(fmaxf(sv[0][reg], sv[1][reg]), fmaxf(sv[2][reg], sv[3][reg]));
      #pragma unroll
      for (int msk = 1; msk < 16; msk <<= 1) m = fmaxf(m, __shfl_xor(m, msk));
      mnew[reg]  = fmaxf(mrow[reg], m);
      alpha[reg] = __expf(mrow[reg] - mnew[reg]);
      ls[reg] = 0.f;
    }
    #pragma unroll
    for (int ct = 0; ct < 4; ++ct)
      #pragma unroll
      for (int reg = 0; reg < 4; ++reg) {
        const float p = __expf(sv[ct][reg] - mnew[reg]);
        ls[reg] += p;
        const int prow = l4 * 4 + reg;
        Ps[wave][prow][(ct * 16 + l15) ^ ((prow & 7) * 8)] = f2bf(p);
      }
    #pragma unroll
    for (int reg = 0; reg < 4; ++reg) {
      float t = ls[reg];
      #pragma unroll
      for (int msk = 1; msk < 16; msk <<= 1) t += __shfl_xor(t, msk);
      lrow[reg] = lrow[reg] * alpha[reg] + t;
      mrow[reg] = mnew[reg];
    }
    #pragma unroll
    for (int ct = 0; ct < 8; ++ct)
      #pragma unroll
      for (int reg = 0; reg < 4; ++reg) o_[ct][reg] *= alpha[reg];
    bf16x8 pa[2];
    #pragma unroll
    for (int kc = 0; kc < 2; ++kc)
      pa[kc] = *reinterpret_cast<const bf16x8*>(
          &Ps[wave][l15][((kc * 4 + l4) ^ swz) * 8]);
    __builtin_amdgcn_s_setprio(1);
    #pragma unroll
    for (int ct = 0; ct < 8; ++ct) {
      #pragma unroll
      for (int kc = 0; kc < 2; ++kc) {
        bf16x8 vb = *reinterpret_cast<const bf16x8*>(
            &Vs[ct * 16 + l15][((kc * 4 + l4) ^ swz) * 8]);
        o_[ct] = __builtin_amdgcn_mfma_f32_16x16x32_bf16(pa[kc], vb, o_[ct], 0, 0, 0);
      }
    }
    __builtin_amdgcn_s_setprio(0);
  }

  if (nchunk == 1) {
    #pragma unroll
    for (int ct = 0; ct < 8; ++ct)
      #pragma unroll
      for (int reg = 0; reg < 4; ++reg) {
        const size_t row = mbase + wave * 16 + l4 * 4 + reg;
        out[row * H_ + ct * 16 + l15] = o_[ct][reg] / lrow[reg];
      }
  } else {
    const size_t slot = ((size_t)(b * 32 + qi)) * 4 + ci;
    ushort* po = pO + slot * 64 * 128;
    #pragma unroll
    for (int ct = 0; ct < 8; ++ct)
      #pragma unroll
      for (int reg = 0; reg < 4; ++reg) {
        const int row = wave * 16 + l4 * 4 + reg;
        po[(size_t)row * 128 + ct * 16 + l15] = f2bf(o_[ct][reg]);
      }
    #pragma unroll
    for (int reg = 0; reg < 4; ++reg) {
      if (l15 == 0) {
        const int row = wave * 16 + l4 * 4 + reg;
        pm[slot * 64 + row] = mrow[reg];
        pl[slot * 64 + row] = lrow[reg];
      }
    }
  }
}

// ---------------- combine partials for qi >= 8 (unchanged) ----------------
__global__ __launch_bounds__(256) void combine_kernel(
    const ushort* __restrict__ pO, const float* __restrict__ pm,
    const float* __restrict__ pl, float* __restrict__ out)
{
  const int o = blockIdx.x;              // 0..191
  const int b = o / 24, qi = 8 + o % 24;
  const int nc = (qi >> 3) + 1;          // 2..4
  const int tid = threadIdx.x;
  const int row = tid >> 2, cg = tid & 3;
  const size_t slotbase = ((size_t)(b * 32 + qi)) * 4;

  float M = -1e30f;
  for (int ci = 0; ci < nc; ++ci)
    M = fmaxf(M, pm[(slotbase + ci) * 64 + row]);

  float L = 0.f;
  float acc[32];
  #pragma unroll
  for (int j = 0; j < 32; ++j) acc[j] = 0.f;
  for (int ci = 0; ci < nc; ++ci) {
    const float e = __expf(pm[(slotbase + ci) * 64 + row] - M);
    L += pl[(slotbase + ci) * 64 + row] * e;
    const ushort* src = pO + (slotbase + ci) * 8192 + (size_t)row * 128 + cg * 32;
    #pragma unroll
    for (int j4 = 0; j4 < 4; ++j4) {
      bf16x8 v = *reinterpret_cast<const bf16x8*>(&src[j4 * 8]);
      #pragma unroll
      for (int j = 0; j < 8; ++j)
        acc[j4 * 8 + j] += e * bf2f((ushort)v[j]);
    }
  }
  const float inv = 1.f / L;
  float* dst = out + ((size_t)b * T_ + qi * 64 + row) * H_ + cg * 32;
  #pragma unroll
  for (int j4 = 0; j4 < 8; ++j4) {
    float4 w;
    w.x = acc[j4 * 4 + 0] * inv; w.y = acc[j4 * 4 + 1] * inv;
    w.z = acc[j4 * 4 + 2] * inv; w.w = acc[j4 * 4 + 3] * inv;
    *reinterpret_cast<float4*>(&dst[j4 * 4]) = w;
  }
}

extern "C" void kernel_launch(void* const* d_in, const int* in_sizes, int n_in,
                              void* d_out, int out_size, void* d_ws, size_t ws_size,
                              hipStream_t stream) {
  const float* x  = (const float*)d_in[0];
  const float* Wq = (const float*)d_in[1];
  const float* Wk = (const float*)d_in[2];
  const float* Wv = (const float*)d_in[3];
  float* out = (float*)d_out;
  ushort* qh = (ushort*)d_ws;                         // [16384][128] bf16
  ushort* kh = qh + (size_t)BT * H_;                  // [16384][128] bf16
  ushort* vt = kh + (size_t)BT * H_;                  // [8][128][2048] bf16
  ushort* wt = vt + (size_t)B_ * H_ * T_;             // [384][1024] bf16
  ushort* pO = wt + (size_t)384 * C_;                 // [8*32*4][64][128] bf16
  float*  pm = (float*)(pO + (size_t)8 * 32 * 4 * 64 * 128);  // [8*32*4][64]
  float*  pl = pm + (size_t)8 * 32 * 4 * 64;
  wtrans_kernel<<<96, 256, 0, stream>>>(Wq, Wk, Wv, wt);
  proj_kernel<<<768, 256, 0, stream>>>(x, wt, qh, kh, vt);
  attn_kernel<<<640, 256, 0, stream>>>(qh, kh, vt, pO, pm, pl, out);
  combine_kernel<<<192, 256, 0, stream>>>(pO, pm, pl, out);
}